// Round 1
// baseline (977.528 us; speedup 1.0000x reference)
//
#include <hip/hip_runtime.h>
#include <cstdint>

#define NBOX 25200
#define NCLS 80
#define NIMG 16
#define KPRE 256
#define MAXB 100
#define SCORE_THR 0.25f
#define IOU_THR 0.1f
#define NBINS 4096
#define GCAP 2048
#define FCAP 8192

__constant__ float c_AW[9] = {10.f,16.f,33.f,30.f,62.f,59.f,116.f,156.f,373.f};
__constant__ float c_AH[9] = {13.f,30.f,23.f,61.f,45.f,119.f,90.f,198.f,326.f};

__device__ __forceinline__ float sigmoidf_(float x) { return 1.0f / (1.0f + expf(-x)); }

// ---------------- Kernel 1: decode boxes (x1y1x2y2) + sigmoid(conf) ----------------
__global__ __launch_bounds__(256) void decode_kernel(
    const float* __restrict__ p5, const float* __restrict__ p4, const float* __restrict__ p3,
    float* __restrict__ boxes, float* __restrict__ conf)
{
  int t = blockIdx.x * 256 + threadIdx.x;
  if (t >= NIMG * NBOX) return;
  int b = t / NBOX, i = t - b * NBOX;
  const float* p; int g, li, abase;
  if (i < 1200)      { p = p5; g = 20; li = i;        abase = 6; }
  else if (i < 6000) { p = p4; g = 40; li = i - 1200; abase = 3; }
  else               { p = p3; g = 80; li = i - 6000; abase = 0; }
  int cell = li / 3, a = li - cell * 3;
  float ratio = 640.0f / (float)g;
  const float* f = p + ((size_t)((size_t)b * g * g + cell) * 255 + a * 85);
  float v0 = f[0], v1 = f[1], v2 = f[2], v3 = f[3], v4 = f[4];
  float cx = (sigmoidf_(v0) + (float)(cell % g)) * ratio;
  float cy = (sigmoidf_(v1) + (float)(cell / g)) * ratio;
  float w = expf(v2) * c_AW[abase + a];
  float h = expf(v3) * c_AH[abase + a];
  float hw = 0.5f * w, hh = 0.5f * h;
  float* ob = boxes + (size_t)t * 4;
  ob[0] = cx - hw; ob[1] = cy - hh; ob[2] = cx + hw; ob[3] = cy + hh;
  conf[t] = sigmoidf_(v4);
}

// score for (b, c, box i), recomputed on the fly (matches ref fp32 rounding)
__device__ __forceinline__ float score_at(
    const float* __restrict__ p5, const float* __restrict__ p4, const float* __restrict__ p3,
    const float* __restrict__ conf, int b, int c, int i)
{
  const float* p; int g, li;
  if (i < 1200)      { p = p5; g = 20; li = i; }
  else if (i < 6000) { p = p4; g = 40; li = i - 1200; }
  else               { p = p3; g = 80; li = i - 6000; }
  int cell = li / 3, a = li - cell * 3;
  float logit = p[(size_t)((size_t)b * g * g + cell) * 255 + a * 85 + 5 + c];
  return __fmul_rn(conf[b * NBOX + i], 1.0f / (1.0f + expf(-logit)));
}

// ---------------- Kernel 2: per-(image,class) top-256 select + NMS ----------------
__global__ __launch_bounds__(256) void select_nms_kernel(
    const float* __restrict__ p5, const float* __restrict__ p4, const float* __restrict__ p3,
    const float* __restrict__ conf, const float* __restrict__ boxes,
    float* __restrict__ kept_s, int* __restrict__ top_i)
{
  const int task = blockIdx.x;               // b*80 + c
  const int b = task / NCLS, c = task - b * NCLS;
  const int tid = threadIdx.x;

  __shared__ uint32_t hist[NBINS];
  __shared__ uint32_t chunkS[256];
  __shared__ unsigned long long keys[GCAP];
  __shared__ float s_lo, s_hi, s_glo;
  __shared__ uint32_t s_above;
  __shared__ int s_state, s_cnt;

  float lo = SCORE_THR, hi = 1.0f;
  uint32_t above = 0;
  float gatherLo = SCORE_THR;
  bool done = false;

  for (int iter = 0; iter < 6 && !done; ++iter) {
    for (int z = tid; z < NBINS; z += 256) hist[z] = 0;
    __syncthreads();
    float scale = (float)NBINS / (hi - lo);
    for (int i = tid; i < NBOX; i += 256) {
      float s = score_at(p5, p4, p3, conf, b, c, i);
      if (s > lo && s <= hi) {
        int bin = (int)((s - lo) * scale);
        bin = bin < 0 ? 0 : (bin > NBINS - 1 ? NBINS - 1 : bin);
        atomicAdd(&hist[bin], 1u);
      }
    }
    __syncthreads();
    { // 16-bin chunk partial sums for fast top-down search
      uint32_t cs = 0; int base = tid * 16;
      #pragma unroll
      for (int z = 0; z < 16; ++z) cs += hist[base + z];
      chunkS[tid] = cs;
    }
    __syncthreads();
    if (tid == 0) {
      uint32_t acc = 0; int ch;
      for (ch = 255; ch >= 0; --ch) {
        if (above + acc + chunkS[ch] >= KPRE) break;
        acc += chunkS[ch];
      }
      if (ch < 0) { s_state = 1; s_glo = SCORE_THR; }
      else {
        int B = -1;
        for (int z = ch * 16 + 15; z >= ch * 16; --z) {
          acc += hist[z];
          if (above + acc >= KPRE) { B = z; break; }
        }
        uint32_t popB = hist[B];
        uint32_t aboveNew = above + acc - popB;
        float wdt = (hi - lo) / (float)NBINS;
        float binLo = lo + (float)B * wdt;
        if (aboveNew + popB <= 1024u || iter == 5) { s_state = 1; s_glo = binLo; }
        else { s_state = 0; s_lo = binLo; s_hi = binLo + wdt; s_above = aboveNew; }
      }
    }
    __syncthreads();
    if (s_state == 1) { gatherLo = s_glo; done = true; }
    else { lo = s_lo; hi = s_hi; above = s_above; }
    __syncthreads();
  }
  // nudge boundary a few ulps down so bin-rounding can't drop a true top-256 entry;
  // strict s > SCORE_THR is still enforced separately.
  gatherLo = __uint_as_float(__float_as_uint(gatherLo) - 8u);

  if (tid == 0) s_cnt = 0;
  __syncthreads();
  for (int i = tid; i < NBOX; i += 256) {
    float s = score_at(p5, p4, p3, conf, b, c, i);
    if (s > gatherLo && s > SCORE_THR) {
      int slot = atomicAdd(&s_cnt, 1);
      if (slot < GCAP)
        keys[slot] = ((unsigned long long)__float_as_uint(s) << 32) | (uint32_t)(0xFFFFFFFFu - (uint32_t)i);
    }
  }
  __syncthreads();
  int n = s_cnt < GCAP ? s_cnt : GCAP;
  for (int z = tid; z < GCAP; z += 256) if (z >= n) keys[z] = 0ull;
  __syncthreads();
  // bitonic sort, descending (key = score_bits<<32 | ~idx -> top_k tie rule: smaller idx first)
  for (int k = 2; k <= GCAP; k <<= 1) {
    for (int j = k >> 1; j > 0; j >>= 1) {
      for (int i2 = tid; i2 < GCAP; i2 += 256) {
        int ixj = i2 ^ j;
        if (ixj > i2) {
          unsigned long long a0 = keys[i2], b0 = keys[ixj];
          bool sw = ((i2 & k) == 0) ? (a0 < b0) : (a0 > b0);
          if (sw) { keys[i2] = b0; keys[ixj] = a0; }
        }
      }
      __syncthreads();
    }
  }

  // ---- NMS on the top-256 (thread r owns candidate r) ----
  __shared__ float bx1[KPRE], by1[KPRE], bx2[KPRE], by2[KPRE], bar_[KPRE], tsc[KPRE];
  __shared__ int tix[KPRE];
  __shared__ unsigned char suppA[KPRE], keepA[KPRE];
  {
    int r = tid;
    unsigned long long kk = keys[r];
    float sc; int idx;
    if ((uint32_t)(kk >> 32) != 0u) { sc = __uint_as_float((uint32_t)(kk >> 32)); idx = (int)(0xFFFFFFFFu - (uint32_t)kk); }
    else { sc = -1.0f; idx = 0; }
    tsc[r] = sc; tix[r] = idx;
    const float* bp = boxes + ((size_t)b * NBOX + idx) * 4;
    float x1 = bp[0], y1 = bp[1], x2 = bp[2], y2 = bp[3];
    bx1[r] = x1; by1[r] = y1; bx2[r] = x2; by2[r] = y2;
    bar_[r] = __fmul_rn(fmaxf(__fsub_rn(x2, x1), 0.0f), fmaxf(__fsub_rn(y2, y1), 0.0f));
    suppA[r] = (sc <= SCORE_THR) ? 1 : 0;
  }
  __syncthreads();
  for (int i = 0; i < KPRE; ++i) {
    if (suppA[i] == 0) {     // uniform branch (all threads read same LDS addr)
      int r = tid;
      if (r > i) {
        float iw = fmaxf(__fsub_rn(fminf(bx2[r], bx2[i]), fmaxf(bx1[r], bx1[i])), 0.0f);
        float ih = fmaxf(__fsub_rn(fminf(by2[r], by2[i]), fmaxf(by1[r], by1[i])), 0.0f);
        float inter = __fmul_rn(iw, ih);
        float uni = __fsub_rn(__fadd_rn(bar_[r], bar_[i]), inter);
        float iou = inter / fmaxf(uni, 1e-9f);
        if (iou > IOU_THR) suppA[r] = 1;
      }
    }
    __syncthreads();
  }
  if (tid == 0) {            // keep first 100 kept (cumsum <= MAX_BOXES)
    int cnt = 0;
    for (int r = 0; r < KPRE; ++r) {
      int kp = (suppA[r] == 0) ? 1 : 0;
      if (kp && cnt < MAXB) cnt++; else kp = 0;
      keepA[r] = (unsigned char)kp;
    }
  }
  __syncthreads();
  {
    int r = tid;
    kept_s[(size_t)task * KPRE + r] = keepA[r] ? tsc[r] : -1.0f;
    top_i[(size_t)task * KPRE + r] = tix[r];
  }
}

// ---------------- Kernel 3: per-image final top-100 ----------------
__global__ __launch_bounds__(256) void final_topk_kernel(
    const float* __restrict__ kept_s, const int* __restrict__ top_i,
    const float* __restrict__ boxes, float* __restrict__ out)
{
  int b = blockIdx.x, tid = threadIdx.x;
  __shared__ unsigned long long keys[FCAP];   // <= 8000 positives guaranteed (<=100/class)
  __shared__ int s_cnt;
  if (tid == 0) s_cnt = 0;
  __syncthreads();
  const float* ks = kept_s + (size_t)b * NCLS * KPRE;
  for (int z = tid; z < NCLS * KPRE; z += 256) {
    float s = ks[z];
    if (s > 0.0f) {
      int slot = atomicAdd(&s_cnt, 1);
      keys[slot] = ((unsigned long long)__float_as_uint(s) << 32) | (uint32_t)(0xFFFFFFFFu - (uint32_t)z);
    }
  }
  __syncthreads();
  int n = s_cnt;
  for (int z = tid; z < FCAP; z += 256) if (z >= n) keys[z] = 0ull;
  __syncthreads();
  for (int k = 2; k <= FCAP; k <<= 1) {
    for (int j = k >> 1; j > 0; j >>= 1) {
      for (int i2 = tid; i2 < FCAP; i2 += 256) {
        int ixj = i2 ^ j;
        if (ixj > i2) {
          unsigned long long a0 = keys[i2], b0 = keys[ixj];
          bool sw = ((i2 & k) == 0) ? (a0 < b0) : (a0 > b0);
          if (sw) { keys[i2] = b0; keys[ixj] = a0; }
        }
      }
      __syncthreads();
    }
  }
  float* ob = out + (size_t)b * MAXB * 4;
  float* os = out + (size_t)NIMG * MAXB * 4 + (size_t)b * MAXB;
  float* ol = out + (size_t)NIMG * MAXB * 4 + (size_t)NIMG * MAXB + (size_t)b * MAXB;
  for (int t = tid; t < MAXB; t += 256) {
    unsigned long long kk = keys[t];
    if ((uint32_t)(kk >> 32) != 0u) {
      float s = __uint_as_float((uint32_t)(kk >> 32));
      int fr = (int)(0xFFFFFFFFu - (uint32_t)kk);     // c*256 + r (class-major flat order)
      int cc = fr >> 8, rr = fr & 255;
      int idx = top_i[((size_t)b * NCLS + cc) * KPRE + rr];
      const float* bp = boxes + ((size_t)b * NBOX + idx) * 4;
      ob[t * 4 + 0] = bp[0]; ob[t * 4 + 1] = bp[1]; ob[t * 4 + 2] = bp[2]; ob[t * 4 + 3] = bp[3];
      os[t] = s; ol[t] = (float)cc;
    } else {
      ob[t * 4 + 0] = -1.0f; ob[t * 4 + 1] = -1.0f; ob[t * 4 + 2] = -1.0f; ob[t * 4 + 3] = -1.0f;
      os[t] = -1.0f; ol[t] = -1.0f;
    }
  }
}

extern "C" void kernel_launch(void* const* d_in, const int* in_sizes, int n_in,
                              void* d_out, int out_size, void* d_ws, size_t ws_size,
                              hipStream_t stream)
{
  const float* p5 = (const float*)d_in[0];
  const float* p4 = (const float*)d_in[1];
  const float* p3 = (const float*)d_in[2];
  float* out = (float*)d_out;

  float* boxes = (float*)d_ws;                            // 16*25200*4 f
  float* conf  = boxes + (size_t)NIMG * NBOX * 4;         // 16*25200 f
  float* kept  = conf  + (size_t)NIMG * NBOX;             // 1280*256 f
  int*   topi  = (int*)(kept + (size_t)NIMG * NCLS * KPRE); // 1280*256 i

  decode_kernel<<<(NIMG * NBOX + 255) / 256, 256, 0, stream>>>(p5, p4, p3, boxes, conf);
  select_nms_kernel<<<NIMG * NCLS, 256, 0, stream>>>(p5, p4, p3, conf, boxes, kept, topi);
  final_topk_kernel<<<NIMG, 256, 0, stream>>>(kept, topi, boxes, out);
}

// Round 2
// 706.379 us; speedup vs baseline: 1.3839x; 1.3839x over previous
//
#include <hip/hip_runtime.h>
#include <cstdint>

#define NBOX 25200
#define NCLS 80
#define NIMG 16
#define KPRE 256
#define MAXB 100
#define SCORE_THR 0.25f
#define IOU_THR 0.1f
#define NBINS 4096
#define GCAP 1024
#define GCAP_OLD 2048
#define FCAP 8192

__constant__ float c_AW[9] = {10.f,16.f,33.f,30.f,62.f,59.f,116.f,156.f,373.f};
__constant__ float c_AH[9] = {13.f,30.f,23.f,61.f,45.f,119.f,90.f,198.f,326.f};

__device__ __forceinline__ float sigmoidf_(float x) { return 1.0f / (1.0f + expf(-x)); }

// map flat box index i -> (feature map, grid, local index, anchor base)
__device__ __forceinline__ void box_loc(int i, const float* p5, const float* p4, const float* p3,
                                        const float*& p, int& g, int& li, int& abase) {
  if (i < 1200)      { p = p5; g = 20; li = i;        abase = 6; }
  else if (i < 6000) { p = p4; g = 40; li = i - 1200; abase = 3; }
  else               { p = p3; g = 80; li = i - 6000; abase = 0; }
}

// ============ Kernel 1 (main path): decode + transpose scores ============
__global__ __launch_bounds__(256) void decode_transpose_kernel(
    const float* __restrict__ p5, const float* __restrict__ p4, const float* __restrict__ p3,
    int b0, int nb, float* __restrict__ boxes, float* __restrict__ scoresT)
{
  int t = blockIdx.x * 256 + threadIdx.x;
  if (t >= nb * NBOX) return;
  int bl = t / NBOX, i = t - bl * NBOX;
  int b = b0 + bl;
  const float* p; int g, li, abase;
  box_loc(i, p5, p4, p3, p, g, li, abase);
  int cell = li / 3, a = li - cell * 3;
  float ratio = 640.0f / (float)g;
  const float* f = p + ((size_t)((size_t)b * g * g + cell) * 255 + a * 85);
  float v0 = f[0], v1 = f[1], v2 = f[2], v3 = f[3], v4 = f[4];
  float cx = (sigmoidf_(v0) + (float)(cell % g)) * ratio;
  float cy = (sigmoidf_(v1) + (float)(cell / g)) * ratio;
  float w = expf(v2) * c_AW[abase + a];
  float h = expf(v3) * c_AH[abase + a];
  float hw = 0.5f * w, hh = 0.5f * h;
  float* ob = boxes + ((size_t)b * NBOX + i) * 4;
  ob[0] = cx - hw; ob[1] = cy - hh; ob[2] = cx + hw; ob[3] = cy + hh;
  float cf = sigmoidf_(v4);
  float* srow = scoresT + (size_t)bl * NCLS * NBOX + i;
  #pragma unroll 4
  for (int c = 0; c < NCLS; ++c) {
    float s = __fmul_rn(cf, 1.0f / (1.0f + expf(-f[5 + c])));
    srow[(size_t)c * NBOX] = s;
  }
}

// ============ Kernel 2 (main path): per-(image,class) top-256 + NMS, coalesced row ============
__global__ __launch_bounds__(256) void select_nms_t_kernel(
    const float* __restrict__ scoresT, const float* __restrict__ boxes,
    int b0, float* __restrict__ kept_s, int* __restrict__ top_i)
{
  const int task_l = blockIdx.x;             // bl*80 + c
  const int bl = task_l / NCLS, c = task_l - bl * NCLS;
  const int b = b0 + bl;
  const int task = b * NCLS + c;
  const int tid = threadIdx.x;
  const float4* row4 = (const float4*)(scoresT + (size_t)task_l * NBOX);  // 16B-aligned (25200*4B rows)

  __shared__ uint32_t hist[NBINS];
  __shared__ uint32_t chunkS[256];
  __shared__ unsigned long long keys[GCAP];
  __shared__ float s_lo, s_hi, s_glo;
  __shared__ uint32_t s_above;
  __shared__ int s_state, s_cnt;

  float lo = SCORE_THR, hi = 1.0f;
  uint32_t above = 0;
  float gatherLo = SCORE_THR;
  bool done = false;

  for (int iter = 0; iter < 4 && !done; ++iter) {
    for (int z = tid; z < NBINS; z += 256) hist[z] = 0;
    __syncthreads();
    float scale = (float)NBINS / (hi - lo);
    for (int j = tid; j < NBOX / 4; j += 256) {
      float4 v = row4[j];
      float ss[4] = {v.x, v.y, v.z, v.w};
      #pragma unroll
      for (int k = 0; k < 4; ++k) {
        float s = ss[k];
        if (s > lo && s <= hi) {
          int bin = (int)((s - lo) * scale);
          bin = bin < 0 ? 0 : (bin > NBINS - 1 ? NBINS - 1 : bin);
          atomicAdd(&hist[bin], 1u);
        }
      }
    }
    __syncthreads();
    {
      uint32_t cs = 0; int base = tid * 16;
      #pragma unroll
      for (int z = 0; z < 16; ++z) cs += hist[base + z];
      chunkS[tid] = cs;
    }
    __syncthreads();
    if (tid == 0) {
      uint32_t acc = 0; int ch;
      for (ch = 255; ch >= 0; --ch) {
        if (above + acc + chunkS[ch] >= KPRE) break;
        acc += chunkS[ch];
      }
      if (ch < 0) { s_state = 1; s_glo = SCORE_THR; }
      else {
        int B = -1;
        for (int z = ch * 16 + 15; z >= ch * 16; --z) {
          acc += hist[z];
          if (above + acc >= KPRE) { B = z; break; }
        }
        uint32_t popB = hist[B];
        uint32_t aboveNew = above + acc - popB;
        float wdt = (hi - lo) / (float)NBINS;
        float binLo = lo + (float)B * wdt;
        if (aboveNew + popB <= 1000u || iter == 3) { s_state = 1; s_glo = binLo; }
        else { s_state = 0; s_lo = binLo; s_hi = binLo + wdt; s_above = aboveNew; }
      }
    }
    __syncthreads();
    if (s_state == 1) { gatherLo = s_glo; done = true; }
    else { lo = s_lo; hi = s_hi; above = s_above; }
    __syncthreads();
  }
  gatherLo = __uint_as_float(__float_as_uint(gatherLo) - 8u);   // ulp nudge vs bin rounding

  if (tid == 0) s_cnt = 0;
  __syncthreads();
  for (int j = tid; j < NBOX / 4; j += 256) {
    float4 v = row4[j];
    float ss[4] = {v.x, v.y, v.z, v.w};
    #pragma unroll
    for (int k = 0; k < 4; ++k) {
      float s = ss[k];
      if (s > gatherLo && s > SCORE_THR) {
        int i = j * 4 + k;
        int slot = atomicAdd(&s_cnt, 1);
        if (slot < GCAP)
          keys[slot] = ((unsigned long long)__float_as_uint(s) << 32) | (uint32_t)(0xFFFFFFFFu - (uint32_t)i);
      }
    }
  }
  __syncthreads();
  int n = s_cnt < GCAP ? s_cnt : GCAP;
  for (int z = tid; z < GCAP; z += 256) if (z >= n) keys[z] = 0ull;
  __syncthreads();
  for (int k = 2; k <= GCAP; k <<= 1) {
    for (int j = k >> 1; j > 0; j >>= 1) {
      for (int i2 = tid; i2 < GCAP; i2 += 256) {
        int ixj = i2 ^ j;
        if (ixj > i2) {
          unsigned long long a0 = keys[i2], b0_ = keys[ixj];
          bool sw = ((i2 & k) == 0) ? (a0 < b0_) : (a0 > b0_);
          if (sw) { keys[i2] = b0_; keys[ixj] = a0; }
        }
      }
      __syncthreads();
    }
  }

  __shared__ float bx1[KPRE], by1[KPRE], bx2[KPRE], by2[KPRE], bar_[KPRE], tsc[KPRE];
  __shared__ int tix[KPRE];
  __shared__ unsigned char suppA[KPRE], keepA[KPRE];
  {
    int r = tid;
    unsigned long long kk = keys[r];
    float sc; int idx;
    if ((uint32_t)(kk >> 32) != 0u) { sc = __uint_as_float((uint32_t)(kk >> 32)); idx = (int)(0xFFFFFFFFu - (uint32_t)kk); }
    else { sc = -1.0f; idx = 0; }
    tsc[r] = sc; tix[r] = idx;
    const float* bp = boxes + ((size_t)b * NBOX + idx) * 4;
    float x1 = bp[0], y1 = bp[1], x2 = bp[2], y2 = bp[3];
    bx1[r] = x1; by1[r] = y1; bx2[r] = x2; by2[r] = y2;
    bar_[r] = __fmul_rn(fmaxf(__fsub_rn(x2, x1), 0.0f), fmaxf(__fsub_rn(y2, y1), 0.0f));
    suppA[r] = (sc <= SCORE_THR) ? 1 : 0;
  }
  __syncthreads();
  for (int i = 0; i < KPRE; ++i) {
    if (suppA[i] == 0) {
      int r = tid;
      if (r > i) {
        float iw = fmaxf(__fsub_rn(fminf(bx2[r], bx2[i]), fmaxf(bx1[r], bx1[i])), 0.0f);
        float ih = fmaxf(__fsub_rn(fminf(by2[r], by2[i]), fmaxf(by1[r], by1[i])), 0.0f);
        float inter = __fmul_rn(iw, ih);
        float uni = __fsub_rn(__fadd_rn(bar_[r], bar_[i]), inter);
        float iou = inter / fmaxf(uni, 1e-9f);
        if (iou > IOU_THR) suppA[r] = 1;
      }
    }
    __syncthreads();
  }
  if (tid == 0) {
    int cnt = 0;
    for (int r = 0; r < KPRE; ++r) {
      int kp = (suppA[r] == 0) ? 1 : 0;
      if (kp && cnt < MAXB) cnt++; else kp = 0;
      keepA[r] = (unsigned char)kp;
    }
  }
  __syncthreads();
  {
    int r = tid;
    kept_s[(size_t)task * KPRE + r] = keepA[r] ? tsc[r] : -1.0f;
    top_i[(size_t)task * KPRE + r] = tix[r];
  }
}

// ============ Fallback path (round-0, strided) — used only if ws too small ============
__global__ __launch_bounds__(256) void decode_kernel(
    const float* __restrict__ p5, const float* __restrict__ p4, const float* __restrict__ p3,
    float* __restrict__ boxes, float* __restrict__ conf)
{
  int t = blockIdx.x * 256 + threadIdx.x;
  if (t >= NIMG * NBOX) return;
  int b = t / NBOX, i = t - b * NBOX;
  const float* p; int g, li, abase;
  box_loc(i, p5, p4, p3, p, g, li, abase);
  int cell = li / 3, a = li - cell * 3;
  float ratio = 640.0f / (float)g;
  const float* f = p + ((size_t)((size_t)b * g * g + cell) * 255 + a * 85);
  float cx = (sigmoidf_(f[0]) + (float)(cell % g)) * ratio;
  float cy = (sigmoidf_(f[1]) + (float)(cell / g)) * ratio;
  float w = expf(f[2]) * c_AW[abase + a];
  float h = expf(f[3]) * c_AH[abase + a];
  float hw = 0.5f * w, hh = 0.5f * h;
  float* ob = boxes + (size_t)t * 4;
  ob[0] = cx - hw; ob[1] = cy - hh; ob[2] = cx + hw; ob[3] = cy + hh;
  conf[t] = sigmoidf_(f[4]);
}

__device__ __forceinline__ float score_at(
    const float* __restrict__ p5, const float* __restrict__ p4, const float* __restrict__ p3,
    const float* __restrict__ conf, int b, int c, int i)
{
  const float* p; int g, li, abase;
  box_loc(i, p5, p4, p3, p, g, li, abase);
  int cell = li / 3, a = li - cell * 3;
  float logit = p[(size_t)((size_t)b * g * g + cell) * 255 + a * 85 + 5 + c];
  return __fmul_rn(conf[b * NBOX + i], 1.0f / (1.0f + expf(-logit)));
}

__global__ __launch_bounds__(256) void select_nms_kernel(
    const float* __restrict__ p5, const float* __restrict__ p4, const float* __restrict__ p3,
    const float* __restrict__ conf, const float* __restrict__ boxes,
    float* __restrict__ kept_s, int* __restrict__ top_i)
{
  const int task = blockIdx.x;
  const int b = task / NCLS, c = task - b * NCLS;
  const int tid = threadIdx.x;
  __shared__ uint32_t hist[NBINS];
  __shared__ uint32_t chunkS[256];
  __shared__ unsigned long long keys[GCAP_OLD];
  __shared__ float s_lo, s_hi, s_glo;
  __shared__ uint32_t s_above;
  __shared__ int s_state, s_cnt;

  float lo = SCORE_THR, hi = 1.0f;
  uint32_t above = 0;
  float gatherLo = SCORE_THR;
  bool done = false;
  for (int iter = 0; iter < 6 && !done; ++iter) {
    for (int z = tid; z < NBINS; z += 256) hist[z] = 0;
    __syncthreads();
    float scale = (float)NBINS / (hi - lo);
    for (int i = tid; i < NBOX; i += 256) {
      float s = score_at(p5, p4, p3, conf, b, c, i);
      if (s > lo && s <= hi) {
        int bin = (int)((s - lo) * scale);
        bin = bin < 0 ? 0 : (bin > NBINS - 1 ? NBINS - 1 : bin);
        atomicAdd(&hist[bin], 1u);
      }
    }
    __syncthreads();
    { uint32_t cs = 0; int base = tid * 16;
      #pragma unroll
      for (int z = 0; z < 16; ++z) cs += hist[base + z];
      chunkS[tid] = cs; }
    __syncthreads();
    if (tid == 0) {
      uint32_t acc = 0; int ch;
      for (ch = 255; ch >= 0; --ch) {
        if (above + acc + chunkS[ch] >= KPRE) break;
        acc += chunkS[ch];
      }
      if (ch < 0) { s_state = 1; s_glo = SCORE_THR; }
      else {
        int B = -1;
        for (int z = ch * 16 + 15; z >= ch * 16; --z) {
          acc += hist[z];
          if (above + acc >= KPRE) { B = z; break; }
        }
        uint32_t popB = hist[B];
        uint32_t aboveNew = above + acc - popB;
        float wdt = (hi - lo) / (float)NBINS;
        float binLo = lo + (float)B * wdt;
        if (aboveNew + popB <= 1024u || iter == 5) { s_state = 1; s_glo = binLo; }
        else { s_state = 0; s_lo = binLo; s_hi = binLo + wdt; s_above = aboveNew; }
      }
    }
    __syncthreads();
    if (s_state == 1) { gatherLo = s_glo; done = true; }
    else { lo = s_lo; hi = s_hi; above = s_above; }
    __syncthreads();
  }
  gatherLo = __uint_as_float(__float_as_uint(gatherLo) - 8u);
  if (tid == 0) s_cnt = 0;
  __syncthreads();
  for (int i = tid; i < NBOX; i += 256) {
    float s = score_at(p5, p4, p3, conf, b, c, i);
    if (s > gatherLo && s > SCORE_THR) {
      int slot = atomicAdd(&s_cnt, 1);
      if (slot < GCAP_OLD)
        keys[slot] = ((unsigned long long)__float_as_uint(s) << 32) | (uint32_t)(0xFFFFFFFFu - (uint32_t)i);
    }
  }
  __syncthreads();
  int n = s_cnt < GCAP_OLD ? s_cnt : GCAP_OLD;
  for (int z = tid; z < GCAP_OLD; z += 256) if (z >= n) keys[z] = 0ull;
  __syncthreads();
  for (int k = 2; k <= GCAP_OLD; k <<= 1) {
    for (int j = k >> 1; j > 0; j >>= 1) {
      for (int i2 = tid; i2 < GCAP_OLD; i2 += 256) {
        int ixj = i2 ^ j;
        if (ixj > i2) {
          unsigned long long a0 = keys[i2], b0_ = keys[ixj];
          bool sw = ((i2 & k) == 0) ? (a0 < b0_) : (a0 > b0_);
          if (sw) { keys[i2] = b0_; keys[ixj] = a0; }
        }
      }
      __syncthreads();
    }
  }
  __shared__ float bx1[KPRE], by1[KPRE], bx2[KPRE], by2[KPRE], bar_[KPRE], tsc[KPRE];
  __shared__ int tix[KPRE];
  __shared__ unsigned char suppA[KPRE], keepA[KPRE];
  { int r = tid;
    unsigned long long kk = keys[r];
    float sc; int idx;
    if ((uint32_t)(kk >> 32) != 0u) { sc = __uint_as_float((uint32_t)(kk >> 32)); idx = (int)(0xFFFFFFFFu - (uint32_t)kk); }
    else { sc = -1.0f; idx = 0; }
    tsc[r] = sc; tix[r] = idx;
    const float* bp = boxes + ((size_t)b * NBOX + idx) * 4;
    float x1 = bp[0], y1 = bp[1], x2 = bp[2], y2 = bp[3];
    bx1[r] = x1; by1[r] = y1; bx2[r] = x2; by2[r] = y2;
    bar_[r] = __fmul_rn(fmaxf(__fsub_rn(x2, x1), 0.0f), fmaxf(__fsub_rn(y2, y1), 0.0f));
    suppA[r] = (sc <= SCORE_THR) ? 1 : 0; }
  __syncthreads();
  for (int i = 0; i < KPRE; ++i) {
    if (suppA[i] == 0) {
      int r = tid;
      if (r > i) {
        float iw = fmaxf(__fsub_rn(fminf(bx2[r], bx2[i]), fmaxf(bx1[r], bx1[i])), 0.0f);
        float ih = fmaxf(__fsub_rn(fminf(by2[r], by2[i]), fmaxf(by1[r], by1[i])), 0.0f);
        float inter = __fmul_rn(iw, ih);
        float uni = __fsub_rn(__fadd_rn(bar_[r], bar_[i]), inter);
        float iou = inter / fmaxf(uni, 1e-9f);
        if (iou > IOU_THR) suppA[r] = 1;
      }
    }
    __syncthreads();
  }
  if (tid == 0) {
    int cnt = 0;
    for (int r = 0; r < KPRE; ++r) {
      int kp = (suppA[r] == 0) ? 1 : 0;
      if (kp && cnt < MAXB) cnt++; else kp = 0;
      keepA[r] = (unsigned char)kp;
    }
  }
  __syncthreads();
  { int r = tid;
    kept_s[(size_t)task * KPRE + r] = keepA[r] ? tsc[r] : -1.0f;
    top_i[(size_t)task * KPRE + r] = tix[r]; }
}

// ============ Kernel 3: per-image final top-100 ============
__global__ __launch_bounds__(256) void final_topk_kernel(
    const float* __restrict__ kept_s, const int* __restrict__ top_i,
    const float* __restrict__ boxes, float* __restrict__ out)
{
  int b = blockIdx.x, tid = threadIdx.x;
  __shared__ unsigned long long keys[FCAP];
  __shared__ int s_cnt;
  if (tid == 0) s_cnt = 0;
  __syncthreads();
  const float* ks = kept_s + (size_t)b * NCLS * KPRE;
  for (int z = tid; z < NCLS * KPRE; z += 256) {
    float s = ks[z];
    if (s > 0.0f) {
      int slot = atomicAdd(&s_cnt, 1);
      keys[slot] = ((unsigned long long)__float_as_uint(s) << 32) | (uint32_t)(0xFFFFFFFFu - (uint32_t)z);
    }
  }
  __syncthreads();
  int n = s_cnt;
  for (int z = tid; z < FCAP; z += 256) if (z >= n) keys[z] = 0ull;
  __syncthreads();
  for (int k = 2; k <= FCAP; k <<= 1) {
    for (int j = k >> 1; j > 0; j >>= 1) {
      for (int i2 = tid; i2 < FCAP; i2 += 256) {
        int ixj = i2 ^ j;
        if (ixj > i2) {
          unsigned long long a0 = keys[i2], b0_ = keys[ixj];
          bool sw = ((i2 & k) == 0) ? (a0 < b0_) : (a0 > b0_);
          if (sw) { keys[i2] = b0_; keys[ixj] = a0; }
        }
      }
      __syncthreads();
    }
  }
  float* ob = out + (size_t)b * MAXB * 4;
  float* os = out + (size_t)NIMG * MAXB * 4 + (size_t)b * MAXB;
  float* ol = out + (size_t)NIMG * MAXB * 4 + (size_t)NIMG * MAXB + (size_t)b * MAXB;
  for (int t = tid; t < MAXB; t += 256) {
    unsigned long long kk = keys[t];
    if ((uint32_t)(kk >> 32) != 0u) {
      float s = __uint_as_float((uint32_t)(kk >> 32));
      int fr = (int)(0xFFFFFFFFu - (uint32_t)kk);
      int cc = fr >> 8, rr = fr & 255;
      int idx = top_i[((size_t)b * NCLS + cc) * KPRE + rr];
      const float* bp = boxes + ((size_t)b * NBOX + idx) * 4;
      ob[t * 4 + 0] = bp[0]; ob[t * 4 + 1] = bp[1]; ob[t * 4 + 2] = bp[2]; ob[t * 4 + 3] = bp[3];
      os[t] = s; ol[t] = (float)cc;
    } else {
      ob[t * 4 + 0] = -1.0f; ob[t * 4 + 1] = -1.0f; ob[t * 4 + 2] = -1.0f; ob[t * 4 + 3] = -1.0f;
      os[t] = -1.0f; ol[t] = -1.0f;
    }
  }
}

extern "C" void kernel_launch(void* const* d_in, const int* in_sizes, int n_in,
                              void* d_out, int out_size, void* d_ws, size_t ws_size,
                              hipStream_t stream)
{
  const float* p5 = (const float*)d_in[0];
  const float* p4 = (const float*)d_in[1];
  const float* p3 = (const float*)d_in[2];
  float* out = (float*)d_out;

  float* boxes = (float*)d_ws;                                  // 16*25200*4 f
  float* kept  = boxes + (size_t)NIMG * NBOX * 4;               // 1280*256 f
  int*   topi  = (int*)(kept + (size_t)NIMG * NCLS * KPRE);     // 1280*256 i
  float* extra = (float*)(topi + (size_t)NIMG * NCLS * KPRE);   // scoresT or conf

  size_t fixed = ((size_t)NIMG * NBOX * 4 + (size_t)NIMG * NCLS * KPRE * 2) * 4;
  size_t perimg = (size_t)NCLS * NBOX * 4;                      // 8.064 MB / image

  int CH = 0;
  for (int k = NIMG; k >= 1; k >>= 1)
    if (fixed + (size_t)k * perimg <= ws_size) { CH = k; break; }

  if (CH > 0) {
    for (int b0 = 0; b0 < NIMG; b0 += CH) {
      int nb = (NIMG - b0) < CH ? (NIMG - b0) : CH;
      decode_transpose_kernel<<<(nb * NBOX + 255) / 256, 256, 0, stream>>>(
          p5, p4, p3, b0, nb, boxes, extra);
      select_nms_t_kernel<<<nb * NCLS, 256, 0, stream>>>(extra, boxes, b0, kept, topi);
    }
  } else {
    float* conf = extra;                                        // 16*25200 f
    decode_kernel<<<(NIMG * NBOX + 255) / 256, 256, 0, stream>>>(p5, p4, p3, boxes, conf);
    select_nms_kernel<<<NIMG * NCLS, 256, 0, stream>>>(p5, p4, p3, conf, boxes, kept, topi);
  }
  final_topk_kernel<<<NIMG, 256, 0, stream>>>(kept, topi, boxes, out);
}

// Round 3
// 391.125 us; speedup vs baseline: 2.4993x; 1.8060x over previous
//
#include <hip/hip_runtime.h>
#include <cstdint>

#define NBOX 25200
#define NCLS 80
#define NIMG 16
#define KPRE 256
#define MAXB 100
#define SCORE_THR 0.25f
#define IOU_THR 0.1f
#define NBINS 4096
#define GCAP 1024
#define GCAP_OLD 2048
#define FK 512

__constant__ float c_AW[9] = {10.f,16.f,33.f,30.f,62.f,59.f,116.f,156.f,373.f};
__constant__ float c_AH[9] = {13.f,30.f,23.f,61.f,45.f,119.f,90.f,198.f,326.f};

__device__ __forceinline__ float sigmoidf_(float x) { return 1.0f / (1.0f + expf(-x)); }

// map flat box index i -> (feature map, grid, local index, anchor base)
__device__ __forceinline__ void box_loc(int i, const float* p5, const float* p4, const float* p3,
                                        const float*& p, int& g, int& li, int& abase) {
  if (i < 1200)      { p = p5; g = 20; li = i;        abase = 6; }
  else if (i < 6000) { p = p4; g = 40; li = i - 1200; abase = 3; }
  else               { p = p3; g = 80; li = i - 6000; abase = 0; }
}

// ============ Kernel 1 (main path): decode + transpose scores ============
__global__ __launch_bounds__(256) void decode_transpose_kernel(
    const float* __restrict__ p5, const float* __restrict__ p4, const float* __restrict__ p3,
    int b0, int nb, float* __restrict__ boxes, float* __restrict__ scoresT)
{
  int t = blockIdx.x * 256 + threadIdx.x;
  if (t >= nb * NBOX) return;
  int bl = t / NBOX, i = t - bl * NBOX;
  int b = b0 + bl;
  const float* p; int g, li, abase;
  box_loc(i, p5, p4, p3, p, g, li, abase);
  int cell = li / 3, a = li - cell * 3;
  float ratio = 640.0f / (float)g;
  const float* f = p + ((size_t)((size_t)b * g * g + cell) * 255 + a * 85);
  float v0 = f[0], v1 = f[1], v2 = f[2], v3 = f[3], v4 = f[4];
  float cx = (sigmoidf_(v0) + (float)(cell % g)) * ratio;
  float cy = (sigmoidf_(v1) + (float)(cell / g)) * ratio;
  float w = expf(v2) * c_AW[abase + a];
  float h = expf(v3) * c_AH[abase + a];
  float hw = 0.5f * w, hh = 0.5f * h;
  float* ob = boxes + ((size_t)b * NBOX + i) * 4;
  ob[0] = cx - hw; ob[1] = cy - hh; ob[2] = cx + hw; ob[3] = cy + hh;
  float cf = sigmoidf_(v4);
  float* srow = scoresT + (size_t)bl * NCLS * NBOX + i;
  #pragma unroll 4
  for (int c = 0; c < NCLS; ++c) {
    float s = __fmul_rn(cf, 1.0f / (1.0f + expf(-f[5 + c])));
    srow[(size_t)c * NBOX] = s;
  }
}

// ============ Kernel 2 (main path): per-(image,class) top-256 + NMS, coalesced row ============
__global__ __launch_bounds__(256) void select_nms_t_kernel(
    const float* __restrict__ scoresT, const float* __restrict__ boxes,
    int b0, float* __restrict__ kept_s, int* __restrict__ top_i)
{
  const int task_l = blockIdx.x;             // bl*80 + c
  const int bl = task_l / NCLS, c = task_l - bl * NCLS;
  const int b = b0 + bl;
  const int task = b * NCLS + c;
  const int tid = threadIdx.x;
  const float4* row4 = (const float4*)(scoresT + (size_t)task_l * NBOX);

  __shared__ uint32_t hist[NBINS];
  __shared__ uint32_t chunkS[256];
  __shared__ unsigned long long keys[GCAP];
  __shared__ float s_lo, s_hi, s_glo;
  __shared__ uint32_t s_above;
  __shared__ int s_state, s_cnt;

  float lo = SCORE_THR, hi = 1.0f;
  uint32_t above = 0;
  float gatherLo = SCORE_THR;
  bool done = false;

  for (int iter = 0; iter < 4 && !done; ++iter) {
    for (int z = tid; z < NBINS; z += 256) hist[z] = 0;
    __syncthreads();
    float scale = (float)NBINS / (hi - lo);
    for (int j = tid; j < NBOX / 4; j += 256) {
      float4 v = row4[j];
      float ss[4] = {v.x, v.y, v.z, v.w};
      #pragma unroll
      for (int k = 0; k < 4; ++k) {
        float s = ss[k];
        if (s > lo && s <= hi) {
          int bin = (int)((s - lo) * scale);
          bin = bin < 0 ? 0 : (bin > NBINS - 1 ? NBINS - 1 : bin);
          atomicAdd(&hist[bin], 1u);
        }
      }
    }
    __syncthreads();
    {
      uint32_t cs = 0; int base = tid * 16;
      #pragma unroll
      for (int z = 0; z < 16; ++z) cs += hist[base + z];
      chunkS[tid] = cs;
    }
    __syncthreads();
    if (tid == 0) {
      uint32_t acc = 0; int ch;
      for (ch = 255; ch >= 0; --ch) {
        if (above + acc + chunkS[ch] >= KPRE) break;
        acc += chunkS[ch];
      }
      if (ch < 0) { s_state = 1; s_glo = SCORE_THR; }
      else {
        int B = -1;
        for (int z = ch * 16 + 15; z >= ch * 16; --z) {
          acc += hist[z];
          if (above + acc >= KPRE) { B = z; break; }
        }
        uint32_t popB = hist[B];
        uint32_t aboveNew = above + acc - popB;
        float wdt = (hi - lo) / (float)NBINS;
        float binLo = lo + (float)B * wdt;
        if (aboveNew + popB <= 1000u || iter == 3) { s_state = 1; s_glo = binLo; }
        else { s_state = 0; s_lo = binLo; s_hi = binLo + wdt; s_above = aboveNew; }
      }
    }
    __syncthreads();
    if (s_state == 1) { gatherLo = s_glo; done = true; }
    else { lo = s_lo; hi = s_hi; above = s_above; }
    __syncthreads();
  }
  gatherLo = __uint_as_float(__float_as_uint(gatherLo) - 8u);   // ulp nudge vs bin rounding

  if (tid == 0) s_cnt = 0;
  __syncthreads();
  for (int j = tid; j < NBOX / 4; j += 256) {
    float4 v = row4[j];
    float ss[4] = {v.x, v.y, v.z, v.w};
    #pragma unroll
    for (int k = 0; k < 4; ++k) {
      float s = ss[k];
      if (s > gatherLo && s > SCORE_THR) {
        int i = j * 4 + k;
        int slot = atomicAdd(&s_cnt, 1);
        if (slot < GCAP)
          keys[slot] = ((unsigned long long)__float_as_uint(s) << 32) | (uint32_t)(0xFFFFFFFFu - (uint32_t)i);
      }
    }
  }
  __syncthreads();
  int n = s_cnt < GCAP ? s_cnt : GCAP;
  for (int z = tid; z < GCAP; z += 256) if (z >= n) keys[z] = 0ull;
  __syncthreads();
  for (int k = 2; k <= GCAP; k <<= 1) {
    for (int j = k >> 1; j > 0; j >>= 1) {
      for (int i2 = tid; i2 < GCAP; i2 += 256) {
        int ixj = i2 ^ j;
        if (ixj > i2) {
          unsigned long long a0 = keys[i2], b0_ = keys[ixj];
          bool sw = ((i2 & k) == 0) ? (a0 < b0_) : (a0 > b0_);
          if (sw) { keys[i2] = b0_; keys[ixj] = a0; }
        }
      }
      __syncthreads();
    }
  }

  __shared__ float bx1[KPRE], by1[KPRE], bx2[KPRE], by2[KPRE], bar_[KPRE], tsc[KPRE];
  __shared__ int tix[KPRE];
  __shared__ unsigned char suppA[KPRE], keepA[KPRE];
  {
    int r = tid;
    unsigned long long kk = keys[r];
    float sc; int idx;
    if ((uint32_t)(kk >> 32) != 0u) { sc = __uint_as_float((uint32_t)(kk >> 32)); idx = (int)(0xFFFFFFFFu - (uint32_t)kk); }
    else { sc = -1.0f; idx = 0; }
    tsc[r] = sc; tix[r] = idx;
    const float* bp = boxes + ((size_t)b * NBOX + idx) * 4;
    float x1 = bp[0], y1 = bp[1], x2 = bp[2], y2 = bp[3];
    bx1[r] = x1; by1[r] = y1; bx2[r] = x2; by2[r] = y2;
    bar_[r] = __fmul_rn(fmaxf(__fsub_rn(x2, x1), 0.0f), fmaxf(__fsub_rn(y2, y1), 0.0f));
    suppA[r] = (sc <= SCORE_THR) ? 1 : 0;
  }
  __syncthreads();
  for (int i = 0; i < KPRE; ++i) {
    if (suppA[i] == 0) {
      int r = tid;
      if (r > i) {
        float iw = fmaxf(__fsub_rn(fminf(bx2[r], bx2[i]), fmaxf(bx1[r], bx1[i])), 0.0f);
        float ih = fmaxf(__fsub_rn(fminf(by2[r], by2[i]), fmaxf(by1[r], by1[i])), 0.0f);
        float inter = __fmul_rn(iw, ih);
        float uni = __fsub_rn(__fadd_rn(bar_[r], bar_[i]), inter);
        float iou = inter / fmaxf(uni, 1e-9f);
        if (iou > IOU_THR) suppA[r] = 1;
      }
    }
    __syncthreads();
  }
  if (tid == 0) {
    int cnt = 0;
    for (int r = 0; r < KPRE; ++r) {
      int kp = (suppA[r] == 0) ? 1 : 0;
      if (kp && cnt < MAXB) cnt++; else kp = 0;
      keepA[r] = (unsigned char)kp;
    }
  }
  __syncthreads();
  {
    int r = tid;
    kept_s[(size_t)task * KPRE + r] = keepA[r] ? tsc[r] : -1.0f;
    top_i[(size_t)task * KPRE + r] = tix[r];
  }
}

// ============ Fallback path (round-0, strided) — used only if ws too small ============
__global__ __launch_bounds__(256) void decode_kernel(
    const float* __restrict__ p5, const float* __restrict__ p4, const float* __restrict__ p3,
    float* __restrict__ boxes, float* __restrict__ conf)
{
  int t = blockIdx.x * 256 + threadIdx.x;
  if (t >= NIMG * NBOX) return;
  int b = t / NBOX, i = t - b * NBOX;
  const float* p; int g, li, abase;
  box_loc(i, p5, p4, p3, p, g, li, abase);
  int cell = li / 3, a = li - cell * 3;
  float ratio = 640.0f / (float)g;
  const float* f = p + ((size_t)((size_t)b * g * g + cell) * 255 + a * 85);
  float cx = (sigmoidf_(f[0]) + (float)(cell % g)) * ratio;
  float cy = (sigmoidf_(f[1]) + (float)(cell / g)) * ratio;
  float w = expf(f[2]) * c_AW[abase + a];
  float h = expf(f[3]) * c_AH[abase + a];
  float hw = 0.5f * w, hh = 0.5f * h;
  float* ob = boxes + (size_t)t * 4;
  ob[0] = cx - hw; ob[1] = cy - hh; ob[2] = cx + hw; ob[3] = cy + hh;
  conf[t] = sigmoidf_(f[4]);
}

__device__ __forceinline__ float score_at(
    const float* __restrict__ p5, const float* __restrict__ p4, const float* __restrict__ p3,
    const float* __restrict__ conf, int b, int c, int i)
{
  const float* p; int g, li, abase;
  box_loc(i, p5, p4, p3, p, g, li, abase);
  int cell = li / 3, a = li - cell * 3;
  float logit = p[(size_t)((size_t)b * g * g + cell) * 255 + a * 85 + 5 + c];
  return __fmul_rn(conf[b * NBOX + i], 1.0f / (1.0f + expf(-logit)));
}

__global__ __launch_bounds__(256) void select_nms_kernel(
    const float* __restrict__ p5, const float* __restrict__ p4, const float* __restrict__ p3,
    const float* __restrict__ conf, const float* __restrict__ boxes,
    float* __restrict__ kept_s, int* __restrict__ top_i)
{
  const int task = blockIdx.x;
  const int b = task / NCLS, c = task - b * NCLS;
  const int tid = threadIdx.x;
  __shared__ uint32_t hist[NBINS];
  __shared__ uint32_t chunkS[256];
  __shared__ unsigned long long keys[GCAP_OLD];
  __shared__ float s_lo, s_hi, s_glo;
  __shared__ uint32_t s_above;
  __shared__ int s_state, s_cnt;

  float lo = SCORE_THR, hi = 1.0f;
  uint32_t above = 0;
  float gatherLo = SCORE_THR;
  bool done = false;
  for (int iter = 0; iter < 6 && !done; ++iter) {
    for (int z = tid; z < NBINS; z += 256) hist[z] = 0;
    __syncthreads();
    float scale = (float)NBINS / (hi - lo);
    for (int i = tid; i < NBOX; i += 256) {
      float s = score_at(p5, p4, p3, conf, b, c, i);
      if (s > lo && s <= hi) {
        int bin = (int)((s - lo) * scale);
        bin = bin < 0 ? 0 : (bin > NBINS - 1 ? NBINS - 1 : bin);
        atomicAdd(&hist[bin], 1u);
      }
    }
    __syncthreads();
    { uint32_t cs = 0; int base = tid * 16;
      #pragma unroll
      for (int z = 0; z < 16; ++z) cs += hist[base + z];
      chunkS[tid] = cs; }
    __syncthreads();
    if (tid == 0) {
      uint32_t acc = 0; int ch;
      for (ch = 255; ch >= 0; --ch) {
        if (above + acc + chunkS[ch] >= KPRE) break;
        acc += chunkS[ch];
      }
      if (ch < 0) { s_state = 1; s_glo = SCORE_THR; }
      else {
        int B = -1;
        for (int z = ch * 16 + 15; z >= ch * 16; --z) {
          acc += hist[z];
          if (above + acc >= KPRE) { B = z; break; }
        }
        uint32_t popB = hist[B];
        uint32_t aboveNew = above + acc - popB;
        float wdt = (hi - lo) / (float)NBINS;
        float binLo = lo + (float)B * wdt;
        if (aboveNew + popB <= 1024u || iter == 5) { s_state = 1; s_glo = binLo; }
        else { s_state = 0; s_lo = binLo; s_hi = binLo + wdt; s_above = aboveNew; }
      }
    }
    __syncthreads();
    if (s_state == 1) { gatherLo = s_glo; done = true; }
    else { lo = s_lo; hi = s_hi; above = s_above; }
    __syncthreads();
  }
  gatherLo = __uint_as_float(__float_as_uint(gatherLo) - 8u);
  if (tid == 0) s_cnt = 0;
  __syncthreads();
  for (int i = tid; i < NBOX; i += 256) {
    float s = score_at(p5, p4, p3, conf, b, c, i);
    if (s > gatherLo && s > SCORE_THR) {
      int slot = atomicAdd(&s_cnt, 1);
      if (slot < GCAP_OLD)
        keys[slot] = ((unsigned long long)__float_as_uint(s) << 32) | (uint32_t)(0xFFFFFFFFu - (uint32_t)i);
    }
  }
  __syncthreads();
  int n = s_cnt < GCAP_OLD ? s_cnt : GCAP_OLD;
  for (int z = tid; z < GCAP_OLD; z += 256) if (z >= n) keys[z] = 0ull;
  __syncthreads();
  for (int k = 2; k <= GCAP_OLD; k <<= 1) {
    for (int j = k >> 1; j > 0; j >>= 1) {
      for (int i2 = tid; i2 < GCAP_OLD; i2 += 256) {
        int ixj = i2 ^ j;
        if (ixj > i2) {
          unsigned long long a0 = keys[i2], b0_ = keys[ixj];
          bool sw = ((i2 & k) == 0) ? (a0 < b0_) : (a0 > b0_);
          if (sw) { keys[i2] = b0_; keys[ixj] = a0; }
        }
      }
      __syncthreads();
    }
  }
  __shared__ float bx1[KPRE], by1[KPRE], bx2[KPRE], by2[KPRE], bar_[KPRE], tsc[KPRE];
  __shared__ int tix[KPRE];
  __shared__ unsigned char suppA[KPRE], keepA[KPRE];
  { int r = tid;
    unsigned long long kk = keys[r];
    float sc; int idx;
    if ((uint32_t)(kk >> 32) != 0u) { sc = __uint_as_float((uint32_t)(kk >> 32)); idx = (int)(0xFFFFFFFFu - (uint32_t)kk); }
    else { sc = -1.0f; idx = 0; }
    tsc[r] = sc; tix[r] = idx;
    const float* bp = boxes + ((size_t)b * NBOX + idx) * 4;
    float x1 = bp[0], y1 = bp[1], x2 = bp[2], y2 = bp[3];
    bx1[r] = x1; by1[r] = y1; bx2[r] = x2; by2[r] = y2;
    bar_[r] = __fmul_rn(fmaxf(__fsub_rn(x2, x1), 0.0f), fmaxf(__fsub_rn(y2, y1), 0.0f));
    suppA[r] = (sc <= SCORE_THR) ? 1 : 0; }
  __syncthreads();
  for (int i = 0; i < KPRE; ++i) {
    if (suppA[i] == 0) {
      int r = tid;
      if (r > i) {
        float iw = fmaxf(__fsub_rn(fminf(bx2[r], bx2[i]), fmaxf(bx1[r], bx1[i])), 0.0f);
        float ih = fmaxf(__fsub_rn(fminf(by2[r], by2[i]), fmaxf(by1[r], by1[i])), 0.0f);
        float inter = __fmul_rn(iw, ih);
        float uni = __fsub_rn(__fadd_rn(bar_[r], bar_[i]), inter);
        float iou = inter / fmaxf(uni, 1e-9f);
        if (iou > IOU_THR) suppA[r] = 1;
      }
    }
    __syncthreads();
  }
  if (tid == 0) {
    int cnt = 0;
    for (int r = 0; r < KPRE; ++r) {
      int kp = (suppA[r] == 0) ? 1 : 0;
      if (kp && cnt < MAXB) cnt++; else kp = 0;
      keepA[r] = (unsigned char)kp;
    }
  }
  __syncthreads();
  { int r = tid;
    kept_s[(size_t)task * KPRE + r] = keepA[r] ? tsc[r] : -1.0f;
    top_i[(size_t)task * KPRE + r] = tix[r]; }
}

// ============ Kernel 3: per-image final top-100 (histogram select, small sort) ============
__global__ __launch_bounds__(256) void final_topk_kernel(
    const float* __restrict__ kept_s, const int* __restrict__ top_i,
    const float* __restrict__ boxes, float* __restrict__ out)
{
  int b = blockIdx.x, tid = threadIdx.x;
  __shared__ uint32_t hist[NBINS];
  __shared__ uint32_t chunkS[256];
  __shared__ unsigned long long keys[FK];
  __shared__ float s_lo, s_hi, s_glo;
  __shared__ uint32_t s_above;
  __shared__ int s_state, s_cnt;
  const float* ks = kept_s + (size_t)b * NCLS * KPRE;
  const int NK = NCLS * KPRE;                 // 20480

  float lo = SCORE_THR, hi = 1.0f;
  uint32_t above = 0;
  float gatherLo = SCORE_THR;
  bool done = false;

  for (int iter = 0; iter < 4 && !done; ++iter) {
    for (int z = tid; z < NBINS; z += 256) hist[z] = 0;
    __syncthreads();
    float scale = (float)NBINS / (hi - lo);
    for (int z = tid; z < NK; z += 256) {
      float s = ks[z];
      if (s > lo && s <= hi) {
        int bin = (int)((s - lo) * scale);
        bin = bin < 0 ? 0 : (bin > NBINS - 1 ? NBINS - 1 : bin);
        atomicAdd(&hist[bin], 1u);
      }
    }
    __syncthreads();
    {
      uint32_t cs = 0; int base = tid * 16;
      #pragma unroll
      for (int z = 0; z < 16; ++z) cs += hist[base + z];
      chunkS[tid] = cs;
    }
    __syncthreads();
    if (tid == 0) {
      uint32_t acc = 0; int ch;
      for (ch = 255; ch >= 0; --ch) {
        if (above + acc + chunkS[ch] >= MAXB) break;
        acc += chunkS[ch];
      }
      if (ch < 0) { s_state = 1; s_glo = SCORE_THR; }   // fewer than 100 positives: take all
      else {
        int B = -1;
        for (int z = ch * 16 + 15; z >= ch * 16; --z) {
          acc += hist[z];
          if (above + acc >= MAXB) { B = z; break; }
        }
        uint32_t popB = hist[B];
        uint32_t aboveNew = above + acc - popB;
        float wdt = (hi - lo) / (float)NBINS;
        float binLo = lo + (float)B * wdt;
        if (aboveNew + popB <= (uint32_t)(FK - 64) || iter == 3) { s_state = 1; s_glo = binLo; }
        else { s_state = 0; s_lo = binLo; s_hi = binLo + wdt; s_above = aboveNew; }
      }
    }
    __syncthreads();
    if (s_state == 1) { gatherLo = s_glo; done = true; }
    else { lo = s_lo; hi = s_hi; above = s_above; }
    __syncthreads();
  }
  gatherLo = __uint_as_float(__float_as_uint(gatherLo) - 8u);   // ulp nudge vs bin rounding

  if (tid == 0) s_cnt = 0;
  __syncthreads();
  for (int z = tid; z < NK; z += 256) {
    float s = ks[z];
    if (s > gatherLo && s > 0.0f) {
      int slot = atomicAdd(&s_cnt, 1);
      if (slot < FK)
        keys[slot] = ((unsigned long long)__float_as_uint(s) << 32) | (uint32_t)(0xFFFFFFFFu - (uint32_t)z);
    }
  }
  __syncthreads();
  int n = s_cnt < FK ? s_cnt : FK;
  for (int z = tid; z < FK; z += 256) if (z >= n) keys[z] = 0ull;
  __syncthreads();
  for (int k = 2; k <= FK; k <<= 1) {
    for (int j = k >> 1; j > 0; j >>= 1) {
      for (int i2 = tid; i2 < FK; i2 += 256) {
        int ixj = i2 ^ j;
        if (ixj > i2) {
          unsigned long long a0 = keys[i2], b0_ = keys[ixj];
          bool sw = ((i2 & k) == 0) ? (a0 < b0_) : (a0 > b0_);
          if (sw) { keys[i2] = b0_; keys[ixj] = a0; }
        }
      }
      __syncthreads();
    }
  }
  float* ob = out + (size_t)b * MAXB * 4;
  float* os = out + (size_t)NIMG * MAXB * 4 + (size_t)b * MAXB;
  float* ol = out + (size_t)NIMG * MAXB * 4 + (size_t)NIMG * MAXB + (size_t)b * MAXB;
  for (int t = tid; t < MAXB; t += 256) {
    unsigned long long kk = keys[t];
    if ((uint32_t)(kk >> 32) != 0u) {
      float s = __uint_as_float((uint32_t)(kk >> 32));
      int fr = (int)(0xFFFFFFFFu - (uint32_t)kk);     // c*256 + r (class-major flat order)
      int cc = fr >> 8, rr = fr & 255;
      int idx = top_i[((size_t)b * NCLS + cc) * KPRE + rr];
      const float* bp = boxes + ((size_t)b * NBOX + idx) * 4;
      ob[t * 4 + 0] = bp[0]; ob[t * 4 + 1] = bp[1]; ob[t * 4 + 2] = bp[2]; ob[t * 4 + 3] = bp[3];
      os[t] = s; ol[t] = (float)cc;
    } else {
      ob[t * 4 + 0] = -1.0f; ob[t * 4 + 1] = -1.0f; ob[t * 4 + 2] = -1.0f; ob[t * 4 + 3] = -1.0f;
      os[t] = -1.0f; ol[t] = -1.0f;
    }
  }
}

extern "C" void kernel_launch(void* const* d_in, const int* in_sizes, int n_in,
                              void* d_out, int out_size, void* d_ws, size_t ws_size,
                              hipStream_t stream)
{
  const float* p5 = (const float*)d_in[0];
  const float* p4 = (const float*)d_in[1];
  const float* p3 = (const float*)d_in[2];
  float* out = (float*)d_out;

  float* boxes = (float*)d_ws;                                  // 16*25200*4 f
  float* kept  = boxes + (size_t)NIMG * NBOX * 4;               // 1280*256 f
  int*   topi  = (int*)(kept + (size_t)NIMG * NCLS * KPRE);     // 1280*256 i
  float* extra = (float*)(topi + (size_t)NIMG * NCLS * KPRE);   // scoresT or conf

  size_t fixed = ((size_t)NIMG * NBOX * 4 + (size_t)NIMG * NCLS * KPRE * 2) * 4;
  size_t perimg = (size_t)NCLS * NBOX * 4;                      // 8.064 MB / image

  int CH = 0;
  for (int k = NIMG; k >= 1; k >>= 1)
    if (fixed + (size_t)k * perimg <= ws_size) { CH = k; break; }

  if (CH > 0) {
    for (int b0 = 0; b0 < NIMG; b0 += CH) {
      int nb = (NIMG - b0) < CH ? (NIMG - b0) : CH;
      decode_transpose_kernel<<<(nb * NBOX + 255) / 256, 256, 0, stream>>>(
          p5, p4, p3, b0, nb, boxes, extra);
      select_nms_t_kernel<<<nb * NCLS, 256, 0, stream>>>(extra, boxes, b0, kept, topi);
    }
  } else {
    float* conf = extra;                                        // 16*25200 f
    decode_kernel<<<(NIMG * NBOX + 255) / 256, 256, 0, stream>>>(p5, p4, p3, boxes, conf);
    select_nms_kernel<<<NIMG * NCLS, 256, 0, stream>>>(p5, p4, p3, conf, boxes, kept, topi);
  }
  final_topk_kernel<<<NIMG, 256, 0, stream>>>(kept, topi, boxes, out);
}